// Round 1
// baseline (202.064 us; speedup 1.0000x reference)
//
#include <hip/hip_runtime.h>

// Problem: B=8192, T=128, D=7, I=128, C=10, H=64, L=128
// Inputs: 0 x(B,I) 1 feature_mask(T,D,I) 2 thresholds(T,D) 3 leaf_outputs(T,L,C)
//         4 W1(I,H) 5 b1(H) 6 W2(H,T) 7 b2(T)
// Out: (B,C) f32
//
// ws layout (floats):
//   sT      [896][8192]      off 0         (7,340,032)
//   LPpad   [16384][12]      off 7,340,032 (196,608)
//   attnT   [128][8192]      off 7,536,640 (1,048,576)
//   partial [16][8192][10]   off 8,585,216 (1,310,720)
// total 9,895,936 floats = 39.6 MB

#define BB 8192
#define TT 128
#define DD 7
#define II 128
#define CC 10
#define HH 64
#define LL 128

#define OFF_S   0
#define OFF_LP  7340032
#define OFF_AT  7536640
#define OFF_PT  8585216

// ---------------- Kernel 1: z GEMM + softsign, output transposed sT[td][b] --
__global__ __launch_bounds__(256) void zs_kernel(
    const float* __restrict__ mask, const float* __restrict__ x,
    const float* __restrict__ thr, float* __restrict__ sT) {
  __shared__ float As[128][68];  // As[k][m]  m = td-local
  __shared__ float Bs[128][68];  // Bs[k][n]  n = b-local
  const int nt = blockIdx.x;     // 0..127 over b
  const int mt = blockIdx.y;     // 0..13  over td
  const int tid = threadIdx.x;

#pragma unroll
  for (int j = 0; j < 8; ++j) {
    int f4 = tid + 256 * j;          // 0..2047
    int r = f4 >> 5, k4 = f4 & 31;   // row in tile, float4 index along k
    float4 a = ((const float4*)(mask + (size_t)(mt * 64 + r) * 128))[k4];
    As[k4 * 4 + 0][r] = a.x; As[k4 * 4 + 1][r] = a.y;
    As[k4 * 4 + 2][r] = a.z; As[k4 * 4 + 3][r] = a.w;
    float4 b = ((const float4*)(x + (size_t)(nt * 64 + r) * 128))[k4];
    Bs[k4 * 4 + 0][r] = b.x; Bs[k4 * 4 + 1][r] = b.y;
    Bs[k4 * 4 + 2][r] = b.z; Bs[k4 * 4 + 3][r] = b.w;
  }
  __syncthreads();

  const int m0 = (tid & 15) * 4;
  const int n0 = (tid >> 4) * 4;
  float acc[4][4];
#pragma unroll
  for (int i = 0; i < 4; ++i)
#pragma unroll
    for (int j = 0; j < 4; ++j) acc[i][j] = 0.f;

#pragma unroll 4
  for (int k = 0; k < 128; ++k) {
    float4 a = *(const float4*)&As[k][m0];
    float4 b = *(const float4*)&Bs[k][n0];
    float am[4] = {a.x, a.y, a.z, a.w};
    float bn[4] = {b.x, b.y, b.z, b.w};
#pragma unroll
    for (int i = 0; i < 4; ++i)
#pragma unroll
      for (int j = 0; j < 4; ++j) acc[i][j] = fmaf(am[i], bn[j], acc[i][j]);
  }

#pragma unroll
  for (int i = 0; i < 4; ++i) {
    int m = mt * 64 + m0 + i;          // global td index
    float th = thr[m];
    float4 o;
    float z0 = acc[i][0] - th, z1 = acc[i][1] - th, z2 = acc[i][2] - th, z3 = acc[i][3] - th;
    o.x = 0.5f * (z0 / (1.f + fabsf(z0)) + 1.f);
    o.y = 0.5f * (z1 / (1.f + fabsf(z1)) + 1.f);
    o.z = 0.5f * (z2 / (1.f + fabsf(z2)) + 1.f);
    o.w = 0.5f * (z3 / (1.f + fabsf(z3)) + 1.f);
    *(float4*)(sT + (size_t)m * BB + nt * 64 + n0) = o;
  }
}

// ---------------- Kernel 2: leaf softmax, padded to 12 ----------------------
__global__ __launch_bounds__(256) void leafsm_kernel(
    const float* __restrict__ lo, float* __restrict__ lp) {
  int idx = blockIdx.x * 256 + threadIdx.x;  // 0..16383 = (t,l)
  const float* row = lo + (size_t)idx * CC;
  float v[CC];
  float m = -1e30f;
#pragma unroll
  for (int c = 0; c < CC; ++c) { v[c] = row[c]; m = fmaxf(m, v[c]); }
  float s = 0.f;
#pragma unroll
  for (int c = 0; c < CC; ++c) { v[c] = __expf(v[c] - m); s += v[c]; }
  float inv = 1.f / s;
  float* o = lp + (size_t)idx * 12;
#pragma unroll
  for (int c = 0; c < CC; ++c) o[c] = v[c] * inv;
  o[10] = 0.f; o[11] = 0.f;
}

// ---------------- Kernel 3: attention MLP + softmax, output attnT[t][b] -----
__global__ __launch_bounds__(256) void attn_kernel(
    const float* __restrict__ x, const float* __restrict__ W1,
    const float* __restrict__ b1, const float* __restrict__ W2,
    const float* __restrict__ b2, float* __restrict__ attnT) {
  __shared__ float W1s[II * HH];   // [i][h]
  __shared__ float W2s[HH * TT];   // [h][t]
  __shared__ float xs[16 * II];
  __shared__ float hid[16 * HH];
  __shared__ float lgt[16 * TT];
  __shared__ float mred[16], sred[16];
  const int tid = threadIdx.x;
  const int bbase = blockIdx.x * 16;

#pragma unroll
  for (int j = 0; j < 8; ++j) ((float4*)W1s)[tid + 256 * j] = ((const float4*)W1)[tid + 256 * j];
#pragma unroll
  for (int j = 0; j < 8; ++j) ((float4*)W2s)[tid + 256 * j] = ((const float4*)W2)[tid + 256 * j];
#pragma unroll
  for (int j = 0; j < 2; ++j)
    ((float4*)xs)[tid + 256 * j] = ((const float4*)(x + (size_t)bbase * II))[tid + 256 * j];
  __syncthreads();

  // hidden: 16*64 = 1024 dots of length 128
#pragma unroll
  for (int j = 0; j < 4; ++j) {
    int idx = tid + 256 * j;
    int r = idx >> 6, h = idx & 63;
    float acc = b1[h];
    for (int i = 0; i < II; ++i) acc = fmaf(xs[r * II + i], W1s[i * HH + h], acc);
    hid[idx] = fmaxf(acc, 0.f);
  }
  __syncthreads();

  // logits: 16*128 = 2048 dots of length 64
#pragma unroll
  for (int j = 0; j < 8; ++j) {
    int idx = tid + 256 * j;
    int r = idx >> 7, t = idx & 127;
    float acc = b2[t];
    for (int h = 0; h < HH; ++h) acc = fmaf(hid[r * HH + h], W2s[h * TT + t], acc);
    lgt[idx] = acc;
  }
  __syncthreads();

  if (tid < 16) {
    float m = -1e30f;
    for (int t = 0; t < TT; ++t) m = fmaxf(m, lgt[tid * TT + t]);
    float s = 0.f;
    for (int t = 0; t < TT; ++t) s += __expf(lgt[tid * TT + t] - m);
    mred[tid] = m; sred[tid] = 1.f / s;
  }
  __syncthreads();

#pragma unroll
  for (int j = 0; j < 8; ++j) {
    int idx = tid + 256 * j;
    int r = idx & 15, t = idx >> 4;   // t in 0..127
    float a = __expf(lgt[r * TT + t] - mred[r]) * sred[r];
    attnT[(size_t)t * BB + bbase + r] = a;
  }
}

// ---------------- Kernel 4: main contraction --------------------------------
// grid (64 b-groups of 128, 16 t-chunks of 8); block 256 = 4 waves.
// wave w handles trees {w*2, w*2+1} of the chunk; lane handles b0 and b0+64.
__global__ __launch_bounds__(256) void main_kernel(
    const float* __restrict__ sT, const float* __restrict__ attnT,
    const float* __restrict__ lp, float* __restrict__ partial) {
  __shared__ float LP8[8 * 128 * 12];       // 48 KB
  __shared__ float red[4][128][10];         // 20 KB
  const int bg = blockIdx.x, tc = blockIdx.y;
  const int tid = threadIdx.x;

#pragma unroll
  for (int j = 0; j < 12; ++j)
    ((float4*)LP8)[tid + 256 * j] =
        ((const float4*)(lp + (size_t)tc * 8 * 128 * 12))[tid + 256 * j];
  __syncthreads();

  const int w = tid >> 6, lane = tid & 63;
  const int b0 = bg * 128 + lane;

  float acc0[10], acc1[10];
#pragma unroll
  for (int c = 0; c < 10; ++c) { acc0[c] = 0.f; acc1[c] = 0.f; }

  for (int it = 0; it < 2; ++it) {
    const int tt = w * 2 + it;
    const int t = tc * 8 + tt;
    float sa[7], sb[7];
#pragma unroll
    for (int d = 0; d < 7; ++d) {
      sa[d] = sT[(size_t)(t * 7 + d) * BB + b0];
      sb[d] = sT[(size_t)(t * 7 + d) * BB + b0 + 64];
    }
    const float A0 = attnT[(size_t)t * BB + b0];
    const float A1 = attnT[(size_t)t * BB + b0 + 64];

    // phi_lo over depths 0..2 (bit d of leaf selects s_d (0) or 1-s_d (1))
    float pl0[8], pl1[8], ph0[16], ph1[16];
    {
      float t2[4];
      t2[0] = sa[0] * sa[1]; t2[1] = (1.f - sa[0]) * sa[1];
      t2[2] = sa[0] * (1.f - sa[1]); t2[3] = (1.f - sa[0]) * (1.f - sa[1]);
#pragma unroll
      for (int j = 0; j < 4; ++j) { pl0[j] = t2[j] * sa[2]; pl0[j + 4] = t2[j] * (1.f - sa[2]); }
      t2[0] = sb[0] * sb[1]; t2[1] = (1.f - sb[0]) * sb[1];
      t2[2] = sb[0] * (1.f - sb[1]); t2[3] = (1.f - sb[0]) * (1.f - sb[1]);
#pragma unroll
      for (int j = 0; j < 4; ++j) { pl1[j] = t2[j] * sb[2]; pl1[j + 4] = t2[j] * (1.f - sb[2]); }
    }
    {
      // phi_hi over depths 3..6, attn folded in
      float g1a = A0 * sa[3], g1b = A0 * (1.f - sa[3]);
      float g2[4];
      g2[0] = g1a * sa[4]; g2[1] = g1b * sa[4];
      g2[2] = g1a * (1.f - sa[4]); g2[3] = g1b * (1.f - sa[4]);
      float g3[8];
#pragma unroll
      for (int j = 0; j < 4; ++j) { g3[j] = g2[j] * sa[5]; g3[j + 4] = g2[j] * (1.f - sa[5]); }
#pragma unroll
      for (int h = 0; h < 8; ++h) { ph0[h] = g3[h] * sa[6]; ph0[h + 8] = g3[h] * (1.f - sa[6]); }
      g1a = A1 * sb[3]; g1b = A1 * (1.f - sb[3]);
      g2[0] = g1a * sb[4]; g2[1] = g1b * sb[4];
      g2[2] = g1a * (1.f - sb[4]); g2[3] = g1b * (1.f - sb[4]);
#pragma unroll
      for (int j = 0; j < 4; ++j) { g3[j] = g2[j] * sb[5]; g3[j + 4] = g2[j] * (1.f - sb[5]); }
#pragma unroll
      for (int h = 0; h < 8; ++h) { ph1[h] = g3[h] * sb[6]; ph1[h + 8] = g3[h] * (1.f - sb[6]); }
    }

    const float4* lpt = (const float4*)(LP8 + tt * 128 * 12);
#pragma unroll
    for (int hi = 0; hi < 16; ++hi) {
      float q0 = ph0[hi], q1 = ph1[hi];
#pragma unroll
      for (int lo2 = 0; lo2 < 8; ++lo2) {
        int l = hi * 8 + lo2;
        float4 va = lpt[l * 3 + 0];
        float4 vb = lpt[l * 3 + 1];
        float4 vc = lpt[l * 3 + 2];
        float p0 = pl0[lo2] * q0, p1 = pl1[lo2] * q1;
        acc0[0] = fmaf(p0, va.x, acc0[0]); acc1[0] = fmaf(p1, va.x, acc1[0]);
        acc0[1] = fmaf(p0, va.y, acc0[1]); acc1[1] = fmaf(p1, va.y, acc1[1]);
        acc0[2] = fmaf(p0, va.z, acc0[2]); acc1[2] = fmaf(p1, va.z, acc1[2]);
        acc0[3] = fmaf(p0, va.w, acc0[3]); acc1[3] = fmaf(p1, va.w, acc1[3]);
        acc0[4] = fmaf(p0, vb.x, acc0[4]); acc1[4] = fmaf(p1, vb.x, acc1[4]);
        acc0[5] = fmaf(p0, vb.y, acc0[5]); acc1[5] = fmaf(p1, vb.y, acc1[5]);
        acc0[6] = fmaf(p0, vb.z, acc0[6]); acc1[6] = fmaf(p1, vb.z, acc1[6]);
        acc0[7] = fmaf(p0, vb.w, acc0[7]); acc1[7] = fmaf(p1, vb.w, acc1[7]);
        acc0[8] = fmaf(p0, vc.x, acc0[8]); acc1[8] = fmaf(p1, vc.x, acc1[8]);
        acc0[9] = fmaf(p0, vc.y, acc0[9]); acc1[9] = fmaf(p1, vc.y, acc1[9]);
      }
    }
  }

#pragma unroll
  for (int c = 0; c < 10; ++c) {
    red[w][lane][c] = acc0[c];
    red[w][lane + 64][c] = acc1[c];
  }
  __syncthreads();

#pragma unroll
  for (int j = 0; j < 5; ++j) {
    int idx = tid + 256 * j;           // 0..1279 = bl*10+c
    int bl = idx / 10, c = idx % 10;
    float v = red[0][bl][c] + red[1][bl][c] + red[2][bl][c] + red[3][bl][c];
    partial[((size_t)tc * BB + bg * 128 + bl) * 10 + c] = v;
  }
}

// ---------------- Kernel 5: final reduce over 16 t-chunks -------------------
__global__ __launch_bounds__(256) void reduce_kernel(
    const float* __restrict__ partial, float* __restrict__ out) {
  int idx = blockIdx.x * 256 + threadIdx.x;  // 0..81919
  float s = 0.f;
#pragma unroll
  for (int tc = 0; tc < 16; ++tc) s += partial[(size_t)tc * (BB * CC) + idx];
  out[idx] = s;
}

// ---------------------------------------------------------------------------
extern "C" void kernel_launch(void* const* d_in, const int* in_sizes, int n_in,
                              void* d_out, int out_size, void* d_ws, size_t ws_size,
                              hipStream_t stream) {
  const float* x    = (const float*)d_in[0];
  const float* mask = (const float*)d_in[1];
  const float* thr  = (const float*)d_in[2];
  const float* lo   = (const float*)d_in[3];
  const float* W1   = (const float*)d_in[4];
  const float* b1   = (const float*)d_in[5];
  const float* W2   = (const float*)d_in[6];
  const float* b2   = (const float*)d_in[7];
  float* out = (float*)d_out;
  float* ws  = (float*)d_ws;

  float* sT      = ws + OFF_S;
  float* LPpad   = ws + OFF_LP;
  float* attnT   = ws + OFF_AT;
  float* partial = ws + OFF_PT;

  zs_kernel<<<dim3(128, 14), 256, 0, stream>>>(mask, x, thr, sT);
  leafsm_kernel<<<64, 256, 0, stream>>>(lo, LPpad);
  attn_kernel<<<512, 256, 0, stream>>>(x, W1, b1, W2, b2, attnT);
  main_kernel<<<dim3(64, 16), 256, 0, stream>>>(sT, attnT, LPpad, partial);
  reduce_kernel<<<320, 256, 0, stream>>>(partial, out);
}